// Round 1
// 428.569 us; speedup vs baseline: 1.0628x; 1.0628x over previous
//
#include <hip/hip_runtime.h>

// Problem constants
#define NN 8192
#define FF 128
#define DD 128
#define HH 2
#define ALPHA 0.3f
#define MAXNNZ 1024

typedef float v4f __attribute__((ext_vector_type(4)));

// ---------------------------------------------------------------------------
// Kernel 1 (fused): blocks 0..127 -> xsum[f] = sum_n x[n,f]  (64 rows/block)
//                   block 128     -> c1[h,f] = Wmap[h,f,:].a1w[h,:], c2 likewise
// ---------------------------------------------------------------------------
__global__ __launch_bounds__(256) void prep_kernel(
    const float* __restrict__ Wmap, const float* __restrict__ a1w,
    const float* __restrict__ a2w, const float* __restrict__ x,
    float* __restrict__ c1, float* __restrict__ c2, float* __restrict__ xsum) {
  int b = blockIdx.x;
  int t = threadIdx.x;
  if (b == 128) {
    int h = t >> 7, f = t & 127;
    const float* wrow = Wmap + ((size_t)h * FF + f) * DD;
    const float* a1 = a1w + h * DD;
    const float* a2 = a2w + h * DD;
    float s1 = 0.f, s2 = 0.f;
    #pragma unroll 8
    for (int d = 0; d < DD; d++) {
      float w = wrow[d];
      s1 += w * a1[d];
      s2 += w * a2[d];
    }
    c1[t] = s1;
    c2[t] = s2;
  } else {
    int f = t & 127, rh = t >> 7;
    const float* xp = x + ((size_t)(b * 64 + rh) * FF) + f;
    float s = 0.f;
    #pragma unroll 8
    for (int r = 0; r < 64; r += 2) s += xp[(size_t)r * FF];
    atomicAdd(&xsum[f], s);   // 256 adds per address total -> negligible
  }
}

// ---------------------------------------------------------------------------
// Kernel 2: sa1[h,n] = x[n,:].c1[h,:] + a1_b[h]; sa2 likewise. (unchanged)
// ---------------------------------------------------------------------------
__global__ __launch_bounds__(128) void sa_kernel(
    const float* __restrict__ x, const float* __restrict__ c1,
    const float* __restrict__ c2, const float* __restrict__ a1b,
    const float* __restrict__ a2b, float* __restrict__ sa1, float* __restrict__ sa2) {
  int n = blockIdx.x;
  int f = threadIdx.x;
  float xv = x[(size_t)n * FF + f];
  float p00 = xv * c1[f];
  float p01 = xv * c1[FF + f];
  float p10 = xv * c2[f];
  float p11 = xv * c2[FF + f];
  #pragma unroll
  for (int o = 32; o > 0; o >>= 1) {
    p00 += __shfl_down(p00, o);
    p01 += __shfl_down(p01, o);
    p10 += __shfl_down(p10, o);
    p11 += __shfl_down(p11, o);
  }
  __shared__ float part[2][4];
  int w = f >> 6;
  if ((f & 63) == 0) {
    part[w][0] = p00; part[w][1] = p01; part[w][2] = p10; part[w][3] = p11;
  }
  __syncthreads();
  if (f == 0) {
    sa1[n]      = part[0][0] + part[1][0] + a1b[0];
    sa1[NN + n] = part[0][1] + part[1][1] + a1b[1];
    sa2[n]      = part[0][2] + part[1][2] + a2b[0];
    sa2[NN + n] = part[0][3] + part[1][3] + a2b[1];
  }
}

// ---------------------------------------------------------------------------
// Kernel 3: colsum[h,d] = sum_f xsum[f] * kern[h,f,d]   (tiny GEMV, 2 blocks)
// ---------------------------------------------------------------------------
__global__ __launch_bounds__(128) void colsum_kernel(
    const float* __restrict__ xsum, const float* __restrict__ kern,
    float* __restrict__ colsum) {
  int h = blockIdx.x, d = threadIdx.x;
  const float* kb = kern + (size_t)h * FF * DD + d;
  float s = 0.f;
  #pragma unroll 8
  for (int f = 0; f < FF; f++) s += xsum[f] * kb[(size_t)f * DD];
  colsum[h * DD + d] = s;
}

// ---------------------------------------------------------------------------
// Kernel 4: main sparse kernel. One block (256 thr) per row i.
//   Phase A : nontemporal float4-scan of adj row -> compact indices in LDS.
//             (nt => evict-first: the 268 MB stream doesn't flush x out of L2)
//   Phase B1: per-edge em1 = exp(leaky(s)) - 1 for both heads; reduce sums.
//   Phase B2: gather x rows (4 MB footprint, L2-resident), both heads share
//             one read; 2-way k-split halves the serial chain.
//   Output  : gs[i, h*128+f] = 0.5 * g_h[f] / denom_h ;  cinv[h,i] = 0.5/denom_h
// ---------------------------------------------------------------------------
__global__ __launch_bounds__(256) void gat_gather(
    const float* __restrict__ adj, const float* __restrict__ x,
    const float* __restrict__ sa1, const float* __restrict__ sa2,
    float* __restrict__ gs, float* __restrict__ cinv) {
  int i = blockIdx.x;
  __shared__ int idxbuf[MAXNNZ];
  __shared__ float em1buf[HH][MAXNNZ];
  __shared__ int cnt;
  __shared__ float wred[4][HH];
  __shared__ float sume_sh[HH];
  __shared__ float red2[HH][FF];
  int t = threadIdx.x;
  if (t == 0) cnt = 0;
  __syncthreads();

  // ---- Phase A ----
  const v4f* arow = (const v4f*)(adj + (size_t)i * NN);
  #pragma unroll
  for (int q = 0; q < 8; q++) {
    int f4 = q * 256 + t;               // 0..2047
    v4f a = __builtin_nontemporal_load(&arow[f4]);
    int j0 = f4 * 4;
    if (a.x != 0.f) { int p = atomicAdd(&cnt, 1); if (p < MAXNNZ) idxbuf[p] = j0; }
    if (a.y != 0.f) { int p = atomicAdd(&cnt, 1); if (p < MAXNNZ) idxbuf[p] = j0 + 1; }
    if (a.z != 0.f) { int p = atomicAdd(&cnt, 1); if (p < MAXNNZ) idxbuf[p] = j0 + 2; }
    if (a.w != 0.f) { int p = atomicAdd(&cnt, 1); if (p < MAXNNZ) idxbuf[p] = j0 + 3; }
  }
  __syncthreads();
  int count = min(cnt, MAXNNZ);

  // ---- Phase B1 ----
  float s10 = sa1[i];
  float s11 = sa1[NN + i];
  float l0 = 0.f, l1 = 0.f;
  for (int k = t; k < count; k += 256) {
    int j = idxbuf[k];
    float w0 = s10 + sa2[j];
    float w1 = s11 + sa2[NN + j];
    w0 = (w0 >= 0.f) ? w0 : ALPHA * w0;
    w1 = (w1 >= 0.f) ? w1 : ALPHA * w1;
    float e0 = __expf(w0) - 1.f;
    float e1 = __expf(w1) - 1.f;
    em1buf[0][k] = e0;
    em1buf[1][k] = e1;
    l0 += e0;
    l1 += e1;
  }
  #pragma unroll
  for (int o = 32; o > 0; o >>= 1) {
    l0 += __shfl_down(l0, o);
    l1 += __shfl_down(l1, o);
  }
  int wid = t >> 6;
  if ((t & 63) == 0) { wred[wid][0] = l0; wred[wid][1] = l1; }
  __syncthreads();
  if (t == 0) {
    sume_sh[0] = wred[0][0] + wred[1][0] + wred[2][0] + wred[3][0];
    sume_sh[1] = wred[0][1] + wred[1][1] + wred[2][1] + wred[3][1];
  }
  __syncthreads();

  // ---- Phase B2: weighted gather of x rows (shared across heads) ----
  int ks = t >> 7, f = t & 127;      // ks: which half of the edge list
  float a0 = 0.f, a1 = 0.f;
  const float* xb = x + f;
  #pragma unroll 4
  for (int k = ks; k < count; k += 2) {
    int j = idxbuf[k];
    float xv = xb[(size_t)j * FF];
    a0 += em1buf[0][k] * xv;
    a1 += em1buf[1][k] * xv;
  }
  if (ks == 1) { red2[0][f] = a0; red2[1][f] = a1; }
  __syncthreads();
  if (ks == 0) {
    float inv0 = 0.5f / ((float)NN + sume_sh[0]);   // 0.5 = head-mean factor
    float inv1 = 0.5f / ((float)NN + sume_sh[1]);
    float g0 = (a0 + red2[0][f]) * inv0;
    float g1 = (a1 + red2[1][f]) * inv1;
    gs[(size_t)i * (HH * FF) + f]      = g0;
    gs[(size_t)i * (HH * FF) + FF + f] = g1;
    if (f == 0) { cinv[i] = inv0; cinv[NN + i] = inv1; }
  }
}

// ---------------------------------------------------------------------------
// Kernel 5: out = gs @ kern_as_256x128 + epilogue
//   A = gs [8192 x 256]  (K-dim = h*128+f, already scaled by 0.5/denom)
//   B = kern [H,F,D] flattened = [256 x 128]
//   out[i,d] = acc + cinv[0,i]*colsum[0,d] + cinv[1,i]*colsum[1,d]
//              + 0.5*(bias[0,i,d]+bias[1,i,d])
// ---------------------------------------------------------------------------
__global__ __launch_bounds__(256) void out_gemm(
    const float* __restrict__ gs, const float* __restrict__ kern,
    const float* __restrict__ cinv, const float* __restrict__ colsum,
    const float* __restrict__ bias, float* __restrict__ out) {
  int row0 = blockIdx.x * 32;
  __shared__ float Bl[64 * 128];    // 32 KB
  __shared__ float Al[32 * 129];    // 16.5 KB (half of K at a time)
  const float4* Bg4 = (const float4*)kern;                     // 256x128
  const float4* Ag4 = (const float4*)(gs + (size_t)row0 * 256);
  float4* Bl4 = (float4*)Bl;
  int tid = threadIdx.x;
  int cg = tid & 31;                // cols cg*4..cg*4+3
  int rg = tid >> 5;                // rows rg, rg+8, rg+16, rg+24
  float4 acc[4];
  #pragma unroll
  for (int m = 0; m < 4; m++) acc[m] = make_float4(0.f, 0.f, 0.f, 0.f);

  for (int ka = 0; ka < 2; ka++) {
    __syncthreads();                // prior readers of Al done
    // stage A half: 32 rows x 128 k-cols (k = ka*128 ..)
    #pragma unroll
    for (int q = 0; q < 4; q++) {
      int idx = q * 256 + tid;      // 0..1023
      int r = idx >> 5, c4 = idx & 31;
      float4 g = Ag4[r * 64 + ka * 32 + c4];
      Al[r * 129 + c4 * 4 + 0] = g.x;
      Al[r * 129 + c4 * 4 + 1] = g.y;
      Al[r * 129 + c4 * 4 + 2] = g.z;
      Al[r * 129 + c4 * 4 + 3] = g.w;
    }
    #pragma unroll
    for (int kpi = 0; kpi < 2; kpi++) {
      int kp = ka * 2 + kpi;        // 64-row chunk of B
      __syncthreads();              // Al staged + prior Bl readers done
      #pragma unroll
      for (int q = 0; q < 8; q++)
        Bl4[q * 256 + tid] = Bg4[kp * 2048 + q * 256 + tid];
      __syncthreads();
      for (int k2 = 0; k2 < 64; k2++) {
        float4 bv = *(const float4*)&Bl[k2 * 128 + cg * 4];
        #pragma unroll
        for (int m = 0; m < 4; m++) {
          float av = Al[(rg + m * 8) * 129 + kpi * 64 + k2];
          acc[m].x += av * bv.x;
          acc[m].y += av * bv.y;
          acc[m].z += av * bv.z;
          acc[m].w += av * bv.w;
        }
      }
    }
  }

  float4 cs0 = *(const float4*)&colsum[cg * 4];
  float4 cs1 = *(const float4*)&colsum[DD + cg * 4];
  #pragma unroll
  for (int m = 0; m < 4; m++) {
    int r = row0 + rg + m * 8;
    float ci0 = cinv[r];
    float ci1 = cinv[NN + r];
    float4 b0 = *(const float4*)&bias[((size_t)0 * NN + r) * DD + cg * 4];
    float4 b1 = *(const float4*)&bias[((size_t)1 * NN + r) * DD + cg * 4];
    float4 o;
    o.x = acc[m].x + ci0 * cs0.x + ci1 * cs1.x + 0.5f * (b0.x + b1.x);
    o.y = acc[m].y + ci0 * cs0.y + ci1 * cs1.y + 0.5f * (b0.y + b1.y);
    o.z = acc[m].z + ci0 * cs0.z + ci1 * cs1.z + 0.5f * (b0.z + b1.z);
    o.w = acc[m].w + ci0 * cs0.w + ci1 * cs1.w + 0.5f * (b0.w + b1.w);
    *(float4*)&out[(size_t)r * DD + cg * 4] = o;
  }
}

// ---------------------------------------------------------------------------
// Launch
// ---------------------------------------------------------------------------
extern "C" void kernel_launch(void* const* d_in, const int* in_sizes, int n_in,
                              void* d_out, int out_size, void* d_ws, size_t ws_size,
                              hipStream_t stream) {
  const float* x    = (const float*)d_in[0];
  const float* adj  = (const float*)d_in[1];
  const float* Wmap = (const float*)d_in[2];
  const float* a1w  = (const float*)d_in[3];
  const float* a1b  = (const float*)d_in[4];
  const float* a2w  = (const float*)d_in[5];
  const float* a2b  = (const float*)d_in[6];
  const float* kern = (const float*)d_in[7];
  const float* bias = (const float*)d_in[8];
  float* out = (float*)d_out;
  float* ws  = (float*)d_ws;

  // workspace layout (floats)
  float* c1     = ws;            // 256
  float* c2     = ws + 256;      // 256
  float* sa1    = ws + 512;      // 16384
  float* sa2    = ws + 16896;    // 16384
  float* xsum   = ws + 33280;    // 128
  float* colsum = ws + 33408;    // 256
  float* cinv   = ws + 33664;    // 16384
  float* gs     = ws + 50048;    // 8192*256 = 2097152

  hipMemsetAsync(xsum, 0, FF * sizeof(float), stream);
  prep_kernel<<<129, 256, 0, stream>>>(Wmap, a1w, a2w, x, c1, c2, xsum);
  sa_kernel<<<NN, 128, 0, stream>>>(x, c1, c2, a1b, a2b, sa1, sa2);
  colsum_kernel<<<HH, 128, 0, stream>>>(xsum, kern, colsum);
  gat_gather<<<NN, 256, 0, stream>>>(adj, x, sa1, sa2, gs, cinv);
  out_gemm<<<NN / 32, 256, 0, stream>>>(gs, kern, cinv, colsum, bias, out);
}

// Round 2
// 418.545 us; speedup vs baseline: 1.0882x; 1.0239x over previous
//
#include <hip/hip_runtime.h>

// Problem constants
#define NN 8192
#define FF 128
#define DD 128
#define HH 2
#define ALPHA 0.3f
#define MAXNNZ 1024

typedef float v4f __attribute__((ext_vector_type(4)));

// ---------------------------------------------------------------------------
// Kernel 1 (fused): blocks 0..127 -> xsum[f] = sum_n x[n,f]  (64 rows/block)
//                   block 128     -> c1[h,f] = Wmap[h,f,:].a1w[h,:], c2 likewise
// ---------------------------------------------------------------------------
__global__ __launch_bounds__(256) void prep_kernel(
    const float* __restrict__ Wmap, const float* __restrict__ a1w,
    const float* __restrict__ a2w, const float* __restrict__ x,
    float* __restrict__ c1, float* __restrict__ c2, float* __restrict__ xsum) {
  int b = blockIdx.x;
  int t = threadIdx.x;
  if (b == 128) {
    int h = t >> 7, f = t & 127;
    const float* wrow = Wmap + ((size_t)h * FF + f) * DD;
    const float* a1 = a1w + h * DD;
    const float* a2 = a2w + h * DD;
    float s1 = 0.f, s2 = 0.f;
    #pragma unroll 8
    for (int d = 0; d < DD; d++) {
      float w = wrow[d];
      s1 += w * a1[d];
      s2 += w * a2[d];
    }
    c1[t] = s1;
    c2[t] = s2;
  } else {
    int f = t & 127, rh = t >> 7;
    const float* xp = x + ((size_t)(b * 64 + rh) * FF) + f;
    float s = 0.f;
    #pragma unroll 8
    for (int r = 0; r < 64; r += 2) s += xp[(size_t)r * FF];
    atomicAdd(&xsum[f], s);   // 256 adds per address total -> negligible
  }
}

// ---------------------------------------------------------------------------
// Kernel 2: sa1[h,n] = x[n,:].c1[h,:] + a1_b[h]; sa2 interleaved per node:
//           sa2p[2n] = head0, sa2p[2n+1] = head1  (one 8B load per edge later)
// ---------------------------------------------------------------------------
__global__ __launch_bounds__(128) void sa_kernel(
    const float* __restrict__ x, const float* __restrict__ c1,
    const float* __restrict__ c2, const float* __restrict__ a1b,
    const float* __restrict__ a2b, float* __restrict__ sa1, float* __restrict__ sa2p) {
  int n = blockIdx.x;
  int f = threadIdx.x;
  float xv = x[(size_t)n * FF + f];
  float p00 = xv * c1[f];
  float p01 = xv * c1[FF + f];
  float p10 = xv * c2[f];
  float p11 = xv * c2[FF + f];
  #pragma unroll
  for (int o = 32; o > 0; o >>= 1) {
    p00 += __shfl_down(p00, o);
    p01 += __shfl_down(p01, o);
    p10 += __shfl_down(p10, o);
    p11 += __shfl_down(p11, o);
  }
  __shared__ float part[2][4];
  int w = f >> 6;
  if ((f & 63) == 0) {
    part[w][0] = p00; part[w][1] = p01; part[w][2] = p10; part[w][3] = p11;
  }
  __syncthreads();
  if (f == 0) {
    sa1[n]      = part[0][0] + part[1][0] + a1b[0];
    sa1[NN + n] = part[0][1] + part[1][1] + a1b[1];
    ((float2*)sa2p)[n] = make_float2(part[0][2] + part[1][2] + a2b[0],
                                     part[0][3] + part[1][3] + a2b[1]);
  }
}

// ---------------------------------------------------------------------------
// Kernel 3: adj row -> compacted column indices (CSR-ish, fixed 1024 stride).
// PURE streaming kernel: nothing but the scan + compaction, so the full
// 32-wave occupancy keeps HBM saturated. nontemporal: evict-first in L2.
// ---------------------------------------------------------------------------
__global__ __launch_bounds__(256) void adj_scan(
    const float* __restrict__ adj, int* __restrict__ counts,
    int* __restrict__ idxw) {
  int i = blockIdx.x;
  __shared__ int idxbuf[MAXNNZ];
  __shared__ int cnt;
  int t = threadIdx.x;
  if (t == 0) cnt = 0;
  __syncthreads();
  const v4f* arow = (const v4f*)(adj + (size_t)i * NN);
  #pragma unroll
  for (int q = 0; q < 8; q++) {
    int f4 = q * 256 + t;               // 0..2047
    v4f a = __builtin_nontemporal_load(&arow[f4]);
    int j0 = f4 * 4;
    if (a.x != 0.f) { int p = atomicAdd(&cnt, 1); if (p < MAXNNZ) idxbuf[p] = j0; }
    if (a.y != 0.f) { int p = atomicAdd(&cnt, 1); if (p < MAXNNZ) idxbuf[p] = j0 + 1; }
    if (a.z != 0.f) { int p = atomicAdd(&cnt, 1); if (p < MAXNNZ) idxbuf[p] = j0 + 2; }
    if (a.w != 0.f) { int p = atomicAdd(&cnt, 1); if (p < MAXNNZ) idxbuf[p] = j0 + 3; }
  }
  __syncthreads();
  int count = min(cnt, MAXNNZ);
  if (t == 0) counts[i] = count;
  int* dst = idxw + (size_t)i * MAXNNZ;
  for (int k = t; k < count; k += 256) dst[k] = idxbuf[k];
}

// ---------------------------------------------------------------------------
// Kernel 4: per-row edge scores + weighted x-gather (all L2-resident data).
//   em1 = exp(leaky(s)) - 1 per head; denom = N + sum(em1).
//   gs[i, h*128+f] = 0.5*(xsum[f] + sum_j em1*x[j,f]) / denom_h
//   (the xsum term absorbs the old colsum GEMV into the output GEMM)
// ---------------------------------------------------------------------------
__global__ __launch_bounds__(256) void edge_gather(
    const int* __restrict__ counts, const int* __restrict__ idxw,
    const float* __restrict__ x, const float* __restrict__ sa1,
    const float* __restrict__ sa2p, const float* __restrict__ xsum,
    float* __restrict__ gs) {
  int i = blockIdx.x;
  __shared__ int idxbuf[MAXNNZ];
  __shared__ float em1buf[HH][MAXNNZ];
  __shared__ float wred[4][HH];
  __shared__ float sume_sh[HH];
  __shared__ v4f vred[HH][8][32];
  int t = threadIdx.x;
  int count = counts[i];
  const int* src = idxw + (size_t)i * MAXNNZ;
  for (int k = t; k < count; k += 256) idxbuf[k] = src[k];
  __syncthreads();

  // ---- edge scores ----
  float s10 = sa1[i];
  float s11 = sa1[NN + i];
  float l0 = 0.f, l1 = 0.f;
  for (int k = t; k < count; k += 256) {
    int j = idxbuf[k];
    float2 s2 = ((const float2*)sa2p)[j];
    float w0 = s10 + s2.x;
    float w1 = s11 + s2.y;
    w0 = (w0 >= 0.f) ? w0 : ALPHA * w0;
    w1 = (w1 >= 0.f) ? w1 : ALPHA * w1;
    float e0 = __expf(w0) - 1.f;
    float e1 = __expf(w1) - 1.f;
    em1buf[0][k] = e0;
    em1buf[1][k] = e1;
    l0 += e0;
    l1 += e1;
  }
  #pragma unroll
  for (int o = 32; o > 0; o >>= 1) {
    l0 += __shfl_down(l0, o);
    l1 += __shfl_down(l1, o);
  }
  int wid = t >> 6;
  if ((t & 63) == 0) { wred[wid][0] = l0; wred[wid][1] = l1; }
  __syncthreads();
  if (t == 0) {
    sume_sh[0] = wred[0][0] + wred[1][0] + wred[2][0] + wred[3][0];
    sume_sh[1] = wred[0][1] + wred[1][1] + wred[2][1] + wred[3][1];
  }
  __syncthreads();

  // ---- weighted gather: 32 lanes x float4 per row, 8 edge slots in flight ----
  int sub = t & 31;                  // d-group: cols sub*4 .. sub*4+3
  int eg  = t >> 5;                  // edge slot 0..7
  v4f acc0 = {0.f, 0.f, 0.f, 0.f}, acc1 = {0.f, 0.f, 0.f, 0.f};
  const v4f* xb = (const v4f*)x;     // row j = xb[j*32 + sub]
  #pragma unroll 4
  for (int k = eg; k < count; k += 8) {
    int j = idxbuf[k];
    v4f xv = xb[(size_t)j * 32 + sub];
    acc0 += em1buf[0][k] * xv;
    acc1 += em1buf[1][k] * xv;
  }
  vred[0][eg][sub] = acc0;
  vred[1][eg][sub] = acc1;
  __syncthreads();
  if (t < 64) {
    int h = t >> 5, s = t & 31;
    v4f v = vred[h][0][s];
    #pragma unroll
    for (int e = 1; e < 8; e++) v += vred[h][e][s];
    float inv = 0.5f / ((float)NN + sume_sh[h]);
    v4f xs = ((const v4f*)xsum)[s];
    v4f g = (v + xs) * inv;
    ((v4f*)(gs + (size_t)i * (HH * FF)))[h * 32 + s] = g;
  }
}

// ---------------------------------------------------------------------------
// Kernel 5: out = gs @ kern_as_256x128 + 0.5*(bias0+bias1)
//   A = gs [8192 x 256] (pre-scaled, includes the colsum/xsum term)
//   B = kern [H,F,D] flattened = [256 x 128]
//   Inner loop: float4 A-reads along k (8 b128 per 64 FMAs).
// ---------------------------------------------------------------------------
__global__ __launch_bounds__(256) void out_gemm(
    const float* __restrict__ gs, const float* __restrict__ kern,
    const float* __restrict__ bias, float* __restrict__ out) {
  int row0 = blockIdx.x * 32;
  __shared__ float Bl[64 * 128];    // 32 KB
  __shared__ float Al[32 * 132];    // 16.9 KB (half of K; 132 keeps 16B align)
  const float4* Bg4 = (const float4*)kern;                     // 256x128
  const float4* Ag4 = (const float4*)(gs + (size_t)row0 * 256);
  float4* Bl4 = (float4*)Bl;
  int tid = threadIdx.x;
  int cg = tid & 31;                // cols cg*4..cg*4+3
  int rg = tid >> 5;                // rows rg, rg+8, rg+16, rg+24
  v4f acc[4];
  #pragma unroll
  for (int m = 0; m < 4; m++) acc[m] = (v4f){0.f, 0.f, 0.f, 0.f};

  for (int ka = 0; ka < 2; ka++) {
    __syncthreads();                // prior readers of Al done
    #pragma unroll
    for (int q = 0; q < 4; q++) {
      int idx = q * 256 + tid;      // 0..1023
      int r = idx >> 5, c4 = idx & 31;
      float4 g = Ag4[r * 64 + ka * 32 + c4];
      *(float4*)&Al[r * 132 + c4 * 4] = g;
    }
    #pragma unroll
    for (int kpi = 0; kpi < 2; kpi++) {
      int kp = ka * 2 + kpi;        // 64-row chunk of B
      __syncthreads();              // Al staged + prior Bl readers done
      #pragma unroll
      for (int q = 0; q < 8; q++)
        Bl4[q * 256 + tid] = Bg4[kp * 2048 + q * 256 + tid];
      __syncthreads();
      #pragma unroll 4
      for (int kg = 0; kg < 16; kg++) {
        v4f bv0 = *(const v4f*)&Bl[(kg * 4 + 0) * 128 + cg * 4];
        v4f bv1 = *(const v4f*)&Bl[(kg * 4 + 1) * 128 + cg * 4];
        v4f bv2 = *(const v4f*)&Bl[(kg * 4 + 2) * 128 + cg * 4];
        v4f bv3 = *(const v4f*)&Bl[(kg * 4 + 3) * 128 + cg * 4];
        #pragma unroll
        for (int m = 0; m < 4; m++) {
          v4f a4 = *(const v4f*)&Al[(rg + m * 8) * 132 + kpi * 64 + kg * 4];
          acc[m] += a4.x * bv0;
          acc[m] += a4.y * bv1;
          acc[m] += a4.z * bv2;
          acc[m] += a4.w * bv3;
        }
      }
    }
  }

  #pragma unroll
  for (int m = 0; m < 4; m++) {
    int r = row0 + rg + m * 8;
    v4f b0 = *(const v4f*)&bias[((size_t)0 * NN + r) * DD + cg * 4];
    v4f b1 = *(const v4f*)&bias[((size_t)1 * NN + r) * DD + cg * 4];
    v4f o = acc[m] + 0.5f * (b0 + b1);
    *(v4f*)&out[(size_t)r * DD + cg * 4] = o;
  }
}

// ---------------------------------------------------------------------------
// Launch
// ---------------------------------------------------------------------------
extern "C" void kernel_launch(void* const* d_in, const int* in_sizes, int n_in,
                              void* d_out, int out_size, void* d_ws, size_t ws_size,
                              hipStream_t stream) {
  const float* x    = (const float*)d_in[0];
  const float* adj  = (const float*)d_in[1];
  const float* Wmap = (const float*)d_in[2];
  const float* a1w  = (const float*)d_in[3];
  const float* a1b  = (const float*)d_in[4];
  const float* a2w  = (const float*)d_in[5];
  const float* a2b  = (const float*)d_in[6];
  const float* kern = (const float*)d_in[7];
  const float* bias = (const float*)d_in[8];
  float* out = (float*)d_out;
  float* ws  = (float*)d_ws;

  // workspace layout (floats)
  float* c1   = ws;                    // 256
  float* c2   = ws + 256;              // 256
  float* sa1  = ws + 512;              // 2*8192
  float* sa2p = ws + 16896;            // 2*8192 interleaved
  float* xsum = ws + 33280;            // 128
  float* gs   = ws + 33408;            // 8192*256
  int*   counts = (int*)(ws + 2130560);        // 8192
  int*   idxw   = (int*)(ws + 2138752);        // 8192*1024

  hipMemsetAsync(xsum, 0, FF * sizeof(float), stream);
  prep_kernel<<<129, 256, 0, stream>>>(Wmap, a1w, a2w, x, c1, c2, xsum);
  sa_kernel<<<NN, 128, 0, stream>>>(x, c1, c2, a1b, a2b, sa1, sa2p);
  adj_scan<<<NN, 256, 0, stream>>>(adj, counts, idxw);
  edge_gather<<<NN, 256, 0, stream>>>(counts, idxw, x, sa1, sa2p, xsum, gs);
  out_gemm<<<NN / 32, 256, 0, stream>>>(gs, kern, bias, out);
}

// Round 3
// 414.206 us; speedup vs baseline: 1.0996x; 1.0105x over previous
//
#include <hip/hip_runtime.h>

// Problem constants
#define NN 8192
#define FF 128
#define DD 128
#define HH 2
#define ALPHA 0.3f
#define MAXNNZ 1024

typedef float v4f __attribute__((ext_vector_type(4)));

// ---------------------------------------------------------------------------
// Kernel 1 (fused): blocks 0..127 -> xsum[f] = sum_n x[n,f]  (64 rows/block)
//                   block 128     -> c1[h,f] = Wmap[h,f,:].a1w[h,:], c2 likewise
// ---------------------------------------------------------------------------
__global__ __launch_bounds__(256) void prep_kernel(
    const float* __restrict__ Wmap, const float* __restrict__ a1w,
    const float* __restrict__ a2w, const float* __restrict__ x,
    float* __restrict__ c1, float* __restrict__ c2, float* __restrict__ xsum) {
  int b = blockIdx.x;
  int t = threadIdx.x;
  if (b == 128) {
    int h = t >> 7, f = t & 127;
    const float* wrow = Wmap + ((size_t)h * FF + f) * DD;
    const float* a1 = a1w + h * DD;
    const float* a2 = a2w + h * DD;
    float s1 = 0.f, s2 = 0.f;
    #pragma unroll 8
    for (int d = 0; d < DD; d++) {
      float w = wrow[d];
      s1 += w * a1[d];
      s2 += w * a2[d];
    }
    c1[t] = s1;
    c2[t] = s2;
  } else {
    int f = t & 127, rh = t >> 7;
    const float* xp = x + ((size_t)(b * 64 + rh) * FF) + f;
    float s = 0.f;
    #pragma unroll 8
    for (int r = 0; r < 64; r += 2) s += xp[(size_t)r * FF];
    atomicAdd(&xsum[f], s);   // 256 adds per address total -> negligible
  }
}

// ---------------------------------------------------------------------------
// Kernel 2: sa1[h,n] = x[n,:].c1[h,:] + a1_b[h]; sa2 interleaved per node:
//           sa2p[2n] = head0, sa2p[2n+1] = head1  (one 8B load per edge later)
// ---------------------------------------------------------------------------
__global__ __launch_bounds__(128) void sa_kernel(
    const float* __restrict__ x, const float* __restrict__ c1,
    const float* __restrict__ c2, const float* __restrict__ a1b,
    const float* __restrict__ a2b, float* __restrict__ sa1, float* __restrict__ sa2p) {
  int n = blockIdx.x;
  int f = threadIdx.x;
  float xv = x[(size_t)n * FF + f];
  float p00 = xv * c1[f];
  float p01 = xv * c1[FF + f];
  float p10 = xv * c2[f];
  float p11 = xv * c2[FF + f];
  #pragma unroll
  for (int o = 32; o > 0; o >>= 1) {
    p00 += __shfl_down(p00, o);
    p01 += __shfl_down(p01, o);
    p10 += __shfl_down(p10, o);
    p11 += __shfl_down(p11, o);
  }
  __shared__ float part[2][4];
  int w = f >> 6;
  if ((f & 63) == 0) {
    part[w][0] = p00; part[w][1] = p01; part[w][2] = p10; part[w][3] = p11;
  }
  __syncthreads();
  if (f == 0) {
    sa1[n]      = part[0][0] + part[1][0] + a1b[0];
    sa1[NN + n] = part[0][1] + part[1][1] + a1b[1];
    ((float2*)sa2p)[n] = make_float2(part[0][2] + part[1][2] + a2b[0],
                                     part[0][3] + part[1][3] + a2b[1]);
  }
}

// ---------------------------------------------------------------------------
// Kernel 3 (fused stream+gather): one block (256 thr) per row i.
//   Phase A: nontemporal float4-scan of adj row -> compact indices in LDS.
//   Phase B: SINGLE pass over edges: 8 edge-groups x 32 lanes. Per edge:
//            load sa2p[j] (group-uniform 8B, L2), score -> leaky -> exp-1
//            (computed redundantly per lane: 1 VALU op), float4 gather of
//            x[j] shared across both heads, FMA into per-group accumulators,
//            denom partials in-register. No em1 staging, no idx round-trip.
//   Epilogue: reduce 8 groups, add xsum (absorbs colsum GEMV), scale by
//            0.5/denom_h, write gs row.
//   Gather tail of each block overlaps other blocks' HBM stream (8 blk/CU).
// ---------------------------------------------------------------------------
__global__ __launch_bounds__(256) void gat_fused(
    const float* __restrict__ adj, const float* __restrict__ x,
    const float* __restrict__ sa1, const float* __restrict__ sa2p,
    const float* __restrict__ xsum, float* __restrict__ gs) {
  int i = blockIdx.x;
  __shared__ int idxbuf[MAXNNZ];
  __shared__ int cnt;
  __shared__ float esum_sh[8][HH];
  __shared__ v4f vred[HH][8][32];
  int t = threadIdx.x;
  if (t == 0) cnt = 0;
  __syncthreads();

  // ---- Phase A: compact adjacency row ----
  const v4f* arow = (const v4f*)(adj + (size_t)i * NN);
  #pragma unroll
  for (int q = 0; q < 8; q++) {
    int f4 = q * 256 + t;               // 0..2047
    v4f a = __builtin_nontemporal_load(&arow[f4]);
    int j0 = f4 * 4;
    if (a.x != 0.f) { int p = atomicAdd(&cnt, 1); if (p < MAXNNZ) idxbuf[p] = j0; }
    if (a.y != 0.f) { int p = atomicAdd(&cnt, 1); if (p < MAXNNZ) idxbuf[p] = j0 + 1; }
    if (a.z != 0.f) { int p = atomicAdd(&cnt, 1); if (p < MAXNNZ) idxbuf[p] = j0 + 2; }
    if (a.w != 0.f) { int p = atomicAdd(&cnt, 1); if (p < MAXNNZ) idxbuf[p] = j0 + 3; }
  }
  __syncthreads();
  int count = min(cnt, MAXNNZ);

  // ---- Phase B: single-pass score + gather ----
  float s10 = sa1[i];
  float s11 = sa1[NN + i];
  int sub = t & 31;                  // d-group: cols sub*4 .. sub*4+3
  int eg  = t >> 5;                  // edge slot 0..7
  v4f acc0 = {0.f, 0.f, 0.f, 0.f}, acc1 = {0.f, 0.f, 0.f, 0.f};
  float le0 = 0.f, le1 = 0.f;
  const v4f* xb = (const v4f*)x;     // row j = xb[j*32 + sub]
  const float2* s2p = (const float2*)sa2p;
  #pragma unroll 2
  for (int k = eg; k < count; k += 8) {
    int j = idxbuf[k];
    float2 s2 = s2p[j];              // group-uniform load (broadcast)
    v4f xv = xb[(size_t)j * 32 + sub];
    float w0 = s10 + s2.x;
    float w1 = s11 + s2.y;
    w0 = (w0 >= 0.f) ? w0 : ALPHA * w0;
    w1 = (w1 >= 0.f) ? w1 : ALPHA * w1;
    float e0 = __expf(w0) - 1.f;
    float e1 = __expf(w1) - 1.f;
    acc0 += e0 * xv;
    acc1 += e1 * xv;
    le0 += e0;
    le1 += e1;
  }
  vred[0][eg][sub] = acc0;
  vred[1][eg][sub] = acc1;
  if (sub == 0) { esum_sh[eg][0] = le0; esum_sh[eg][1] = le1; }
  __syncthreads();

  // ---- Epilogue: reduce groups, fold xsum, scale, write gs ----
  if (t < 64) {
    int h = t >> 5, s = t & 31;
    v4f v = vred[h][0][s];
    #pragma unroll
    for (int e = 1; e < 8; e++) v += vred[h][e][s];
    float sume = 0.f;
    #pragma unroll
    for (int e = 0; e < 8; e++) sume += esum_sh[e][h];
    float inv = 0.5f / ((float)NN + sume);   // 0.5 = head-mean factor
    v4f xs = ((const v4f*)xsum)[s];
    ((v4f*)(gs + (size_t)i * (HH * FF)))[h * 32 + s] = (v + xs) * inv;
  }
}

// ---------------------------------------------------------------------------
// Kernel 4: out = gs @ kern_as_256x128 + 0.5*(bias0+bias1)
//   A = gs [8192 x 256] (pre-scaled, includes the colsum/xsum term)
//   B = kern [H,F,D] flattened = [256 x 128]
// ---------------------------------------------------------------------------
__global__ __launch_bounds__(256) void out_gemm(
    const float* __restrict__ gs, const float* __restrict__ kern,
    const float* __restrict__ bias, float* __restrict__ out) {
  int row0 = blockIdx.x * 32;
  __shared__ float Bl[64 * 128];    // 32 KB
  __shared__ float Al[32 * 132];    // 16.9 KB (half of K; 132 keeps 16B align)
  const float4* Bg4 = (const float4*)kern;                     // 256x128
  const float4* Ag4 = (const float4*)(gs + (size_t)row0 * 256);
  float4* Bl4 = (float4*)Bl;
  int tid = threadIdx.x;
  int cg = tid & 31;                // cols cg*4..cg*4+3
  int rg = tid >> 5;                // rows rg, rg+8, rg+16, rg+24
  v4f acc[4];
  #pragma unroll
  for (int m = 0; m < 4; m++) acc[m] = (v4f){0.f, 0.f, 0.f, 0.f};

  for (int ka = 0; ka < 2; ka++) {
    __syncthreads();                // prior readers of Al done
    #pragma unroll
    for (int q = 0; q < 4; q++) {
      int idx = q * 256 + tid;      // 0..1023
      int r = idx >> 5, c4 = idx & 31;
      float4 g = Ag4[r * 64 + ka * 32 + c4];
      *(float4*)&Al[r * 132 + c4 * 4] = g;
    }
    #pragma unroll
    for (int kpi = 0; kpi < 2; kpi++) {
      int kp = ka * 2 + kpi;        // 64-row chunk of B
      __syncthreads();              // Al staged + prior Bl readers done
      #pragma unroll
      for (int q = 0; q < 8; q++)
        Bl4[q * 256 + tid] = Bg4[kp * 2048 + q * 256 + tid];
      __syncthreads();
      #pragma unroll 4
      for (int kg = 0; kg < 16; kg++) {
        v4f bv0 = *(const v4f*)&Bl[(kg * 4 + 0) * 128 + cg * 4];
        v4f bv1 = *(const v4f*)&Bl[(kg * 4 + 1) * 128 + cg * 4];
        v4f bv2 = *(const v4f*)&Bl[(kg * 4 + 2) * 128 + cg * 4];
        v4f bv3 = *(const v4f*)&Bl[(kg * 4 + 3) * 128 + cg * 4];
        #pragma unroll
        for (int m = 0; m < 4; m++) {
          v4f a4 = *(const v4f*)&Al[(rg + m * 8) * 132 + kpi * 64 + kg * 4];
          acc[m] += a4.x * bv0;
          acc[m] += a4.y * bv1;
          acc[m] += a4.z * bv2;
          acc[m] += a4.w * bv3;
        }
      }
    }
  }

  #pragma unroll
  for (int m = 0; m < 4; m++) {
    int r = row0 + rg + m * 8;
    v4f b0 = *(const v4f*)&bias[((size_t)0 * NN + r) * DD + cg * 4];
    v4f b1 = *(const v4f*)&bias[((size_t)1 * NN + r) * DD + cg * 4];
    v4f o = acc[m] + 0.5f * (b0 + b1);
    *(v4f*)&out[(size_t)r * DD + cg * 4] = o;
  }
}

// ---------------------------------------------------------------------------
// Launch
// ---------------------------------------------------------------------------
extern "C" void kernel_launch(void* const* d_in, const int* in_sizes, int n_in,
                              void* d_out, int out_size, void* d_ws, size_t ws_size,
                              hipStream_t stream) {
  const float* x    = (const float*)d_in[0];
  const float* adj  = (const float*)d_in[1];
  const float* Wmap = (const float*)d_in[2];
  const float* a1w  = (const float*)d_in[3];
  const float* a1b  = (const float*)d_in[4];
  const float* a2w  = (const float*)d_in[5];
  const float* a2b  = (const float*)d_in[6];
  const float* kern = (const float*)d_in[7];
  const float* bias = (const float*)d_in[8];
  float* out = (float*)d_out;
  float* ws  = (float*)d_ws;

  // workspace layout (floats)
  float* c1   = ws;                    // 256
  float* c2   = ws + 256;              // 256
  float* sa1  = ws + 512;              // 2*8192
  float* sa2p = ws + 16896;            // 2*8192 interleaved
  float* xsum = ws + 33280;            // 128
  float* gs   = ws + 33408;            // 8192*256

  hipMemsetAsync(xsum, 0, FF * sizeof(float), stream);
  prep_kernel<<<129, 256, 0, stream>>>(Wmap, a1w, a2w, x, c1, c2, xsum);
  sa_kernel<<<NN, 128, 0, stream>>>(x, c1, c2, a1b, a2b, sa1, sa2p);
  gat_fused<<<NN, 256, 0, stream>>>(adj, x, sa1, sa2p, xsum, gs);
  out_gemm<<<NN / 32, 256, 0, stream>>>(gs, kern, bias, out);
}